// Round 5
// baseline (223.054 us; speedup 1.0000x reference)
//
#include <hip/hip_runtime.h>
#include <math.h>

#define EPSF 1e-6f

typedef float  f32x4 __attribute__((ext_vector_type(4)));
typedef int    i32x2 __attribute__((ext_vector_type(2)));

struct F3   { float x, y, z; };
struct Quat { float x, y, z, w; };
struct Sim3 { F3 t; Quat q; float s; };

__device__ __forceinline__ float frcp(float x) { return __builtin_amdgcn_rcpf(x); }

__device__ __forceinline__ F3 cross3(F3 a, F3 b) {
    return { a.y*b.z - a.z*b.y, a.z*b.x - a.x*b.z, a.x*b.y - a.y*b.x };
}

__device__ __forceinline__ F3 quat_rotate(Quat q, F3 v) {
    F3 qv { q.x, q.y, q.z };
    F3 uv  = cross3(qv, v);
    F3 cuv = cross3(qv, uv);
    return { v.x + 2.0f*(q.w*uv.x + cuv.x),
             v.y + 2.0f*(q.w*uv.y + cuv.y),
             v.z + 2.0f*(q.w*uv.z + cuv.z) };
}

__device__ __forceinline__ Quat quat_mul(Quat a, Quat b) {
    return {
        a.w*b.x + a.x*b.w + a.y*b.z - a.z*b.y,
        a.w*b.y - a.x*b.z + a.y*b.w + a.z*b.x,
        a.w*b.z + a.x*b.y - a.y*b.x + a.z*b.w,
        a.w*b.w - a.x*b.x - a.y*b.y - a.z*b.z
    };
}

__device__ __forceinline__ Sim3 sim3_inv(Sim3 T) {
    Quat qi { -T.q.x, -T.q.y, -T.q.z, T.q.w };
    float si = frcp(T.s);
    F3 r = quat_rotate(qi, T.t);
    return { { -si*r.x, -si*r.y, -si*r.z }, qi, si };
}

__device__ __forceinline__ Sim3 sim3_mul(Sim3 A, Sim3 B) {
    F3 r = quat_rotate(A.q, B.t);
    return { { A.t.x + A.s*r.x, A.t.y + A.s*r.y, A.t.z + A.s*r.z },
             quat_mul(A.q, B.q), A.s * B.s };
}

__device__ __forceinline__ Sim3 load_sim3(const float* __restrict__ p) {
    f32x4 a = *reinterpret_cast<const f32x4*>(p);
    f32x4 b = *reinterpret_cast<const f32x4*>(p + 4);
    return { {a.x, a.y, a.z}, {a.w, b.x, b.y, b.z}, b.w };
}

// non-temporal (streaming, evict-first) variant for touch-once arrays
__device__ __forceinline__ Sim3 load_sim3_nt(const float* __restrict__ p) {
    f32x4 a = __builtin_nontemporal_load(reinterpret_cast<const f32x4*>(p));
    f32x4 b = __builtin_nontemporal_load(reinterpret_cast<const f32x4*>(p) + 1);
    return { {a.x, a.y, a.z}, {a.w, b.x, b.y, b.z}, b.w };
}

// atan2(y,x) for y >= 0, result in [0, pi]. Max abs err ~2e-7.
__device__ __forceinline__ float fast_atan2_pos(float y, float x) {
    float ax = fabsf(x);
    float mn = fminf(ax, y), mx = fmaxf(ax, y);
    float t  = mn * frcp(mx);
    float t2 = t * t;
    float p = fmaf(t2, -0.0117212f,  0.05265332f);
    p = fmaf(t2, p, -0.11643287f);
    p = fmaf(t2, p,  0.19354346f);
    p = fmaf(t2, p, -0.33262347f);
    p = fmaf(t2, p,  0.99997726f);
    float r = t * p;
    r = (y > ax)   ? 1.57079632679f - r : r;
    r = (x < 0.0f) ? 3.14159265359f - r : r;
    return r;
}

__device__ __forceinline__ void sim3_log(Sim3 T, float out[7]) {
    float qx = T.q.x, qy = T.q.y, qz = T.q.z, qw = T.q.w;
    float nv2 = fmaf(qx, qx, fmaf(qy, qy, qz*qz));
    float nv  = sqrtf(nv2);
    float theta_r = 2.0f * fast_atan2_pos(nv, qw);
    float fac = (nv < EPSF) ? 2.0f : theta_r * frcp(nv);
    float px = fac*qx, py = fac*qy, pz = fac*qz;
    float sigma = __logf(T.s);
    float theta = sqrtf(fmaf(px, px, fmaf(py, py, pz*pz)));

    bool sig_small = fabsf(sigma) < EPSF;
    bool th_small  = theta < EPSF;
    float sg = sig_small ? 1.0f : sigma;
    float th = th_small  ? 1.0f : theta;
    float scale = __expf(sigma);
    float th2 = th*th, sg2 = sg*sg;
    float rsg  = frcp(sg);
    float rth2 = frcp(th2);
    float C = sig_small ? 1.0f : (scale - 1.0f) * rsg;

    // sin(theta), cos(theta) via quaternion half-angle identity
    float inv_q = frcp(nv2 + qw*qw);
    float sth = 2.0f * qw * nv * inv_q;
    float cth = (qw*qw - nv2) * inv_q;

    float A_ss = th_small ? 0.5f        : (1.0f - cth) * rth2;
    float B_ss = th_small ? (1.0f/6.0f) : (th - sth) * frcp(th2 * th);
    float a = scale * sth;
    float b = scale * cth;
    float c = th2 + sg2;
    float rc = frcp(c);
    float A_g = fmaf(a, sg, (1.0f - b)*th) * frcp(th * c);
    float B_g = (C - fmaf(b - 1.0f, sg, a*th) * rc) * rth2;
    float rsg2 = rsg * rsg;
    float A_ts = fmaf(sg - 1.0f, scale, 1.0f) * rsg2;
    float B_ts = fmaf(scale, fmaf(sg, sg - 2.0f, 2.0f), -2.0f) * (0.5f * rsg2 * rsg);
    float A = sig_small ? A_ss : (th_small ? A_ts : A_g);
    float B = sig_small ? B_ss : (th_small ? B_ts : B_g);

    float P01 = -pz, P02 =  py;
    float P10 =  pz, P12 = -px;
    float P20 = -py, P21 =  px;
    float Q00 = P01*P10 + P02*P20;
    float Q01 = P02*P21;
    float Q02 = P01*P12;
    float Q10 = P12*P20;
    float Q11 = P10*P01 + P12*P21;
    float Q12 = P10*P02;
    float Q20 = P21*P10;
    float Q21 = P20*P01;
    float Q22 = P20*P02 + P21*P12;

    float W00 = fmaf(B, Q00, C);
    float W01 = fmaf(A, P01, B*Q01);
    float W02 = fmaf(A, P02, B*Q02);
    float W10 = fmaf(A, P10, B*Q10);
    float W11 = fmaf(B, Q11, C);
    float W12 = fmaf(A, P12, B*Q12);
    float W20 = fmaf(A, P20, B*Q20);
    float W21 = fmaf(A, P21, B*Q21);
    float W22 = fmaf(B, Q22, C);

    float c00 = fmaf(W11, W22, -W12*W21);
    float c01 = fmaf(W12, W20, -W10*W22);
    float c02 = fmaf(W10, W21, -W11*W20);
    float det = fmaf(W00, c00, fmaf(W01, c01, W02*c02));
    float idet = frcp(det);
    float m01 = fmaf(W02, W21, -W01*W22);
    float m02 = fmaf(W01, W12, -W02*W11);
    float m11 = fmaf(W00, W22, -W02*W20);
    float m12 = fmaf(W02, W10, -W00*W12);
    float m21 = fmaf(W01, W20, -W00*W21);
    float m22 = fmaf(W00, W11, -W01*W10);
    float tx = T.t.x, ty = T.t.y, tz = T.t.z;
    out[0] = fmaf(c00, tx, fmaf(m01, ty, m02*tz)) * idet;
    out[1] = fmaf(c01, tx, fmaf(m11, ty, m12*tz)) * idet;
    out[2] = fmaf(c02, tx, fmaf(m21, ty, m22*tz)) * idet;
    out[3] = px; out[4] = py; out[5] = pz; out[6] = sigma;
}

// One full row's residual, given preloaded Sim3s; weights loaded (nt) inside.
__device__ __forceinline__ void compute_row(
        Sim3 Ti, Sim3 Tj, Sim3 Tp, Sim3 To, Sim3 Ta, Sim3 Tb, Sim3 Tl,
        const float* __restrict__ pw, const float* __restrict__ ow,
        float* __restrict__ out, size_t i7) {
    Sim3 delta = sim3_mul(sim3_inv(Ti), Tj);
    float rp[7], ro[7], rl[7];
    sim3_log(sim3_mul(delta, Tp), rp);
    sim3_log(sim3_mul(delta, To), ro);
    sim3_log(sim3_mul(sim3_mul(sim3_inv(Ta), Tb), Tl), rl);
    #pragma unroll
    for (int k = 0; k < 7; ++k) {
        float w1 = __builtin_nontemporal_load(pw + i7 + k);
        float w2 = __builtin_nontemporal_load(ow + i7 + k);
        __builtin_nontemporal_store(fmaf(rp[k], w1, fmaf(ro[k], w2, rl[k])), out + i7 + k);
    }
}

// Two rows per thread (t and t+half): two independent dependency chains per
// wave double the memory-level parallelism that hides gather/LLC latency.
__global__ void __launch_bounds__(256) pgo_kernel(
        const float* __restrict__ Twc,
        const float* __restrict__ Tp_inv,
        const float* __restrict__ To_inv,
        const float* __restrict__ pw,
        const float* __restrict__ ow,
        const int*   __restrict__ edges,
        const float* __restrict__ T_lc,
        float*       __restrict__ out,
        int n, int half) {
    int t = blockIdx.x * blockDim.x + threadIdx.x;
    if (t >= half) return;

    int iA = t;
    int iB = t + half;
    bool hasB = (iB < n);
    int iBc = hasB ? iB : 0;          // clamp loads, guard stores

    size_t a8 = (size_t)iA * 8;
    size_t b8 = (size_t)iBc * 8;

    // ---- issue ALL loads for both rows up front (gathers first) ----
    i32x2 eA = __builtin_nontemporal_load(reinterpret_cast<const i32x2*>(edges) + iA);
    i32x2 eB = __builtin_nontemporal_load(reinterpret_cast<const i32x2*>(edges) + iBc);
    Sim3 TaA = load_sim3(Twc + (size_t)eA.x * 8);
    Sim3 TbA = load_sim3(Twc + (size_t)eA.y * 8);
    Sim3 TaB = load_sim3(Twc + (size_t)eB.x * 8);
    Sim3 TbB = load_sim3(Twc + (size_t)eB.y * 8);
    Sim3 TiA = load_sim3(Twc + a8);
    Sim3 TjA = load_sim3(Twc + a8 + 8);
    Sim3 TiB = load_sim3(Twc + b8);
    Sim3 TjB = load_sim3(Twc + b8 + 8);
    Sim3 TpA = load_sim3_nt(Tp_inv + a8);
    Sim3 TpB = load_sim3_nt(Tp_inv + b8);
    Sim3 ToA = load_sim3_nt(To_inv + a8);
    Sim3 ToB = load_sim3_nt(To_inv + b8);
    Sim3 TlA = load_sim3_nt(T_lc + a8);
    Sim3 TlB = load_sim3_nt(T_lc + b8);

    compute_row(TiA, TjA, TpA, ToA, TaA, TbA, TlA, pw, ow, out, (size_t)iA * 7);
    if (hasB) {
        compute_row(TiB, TjB, TpB, ToB, TaB, TbB, TlB, pw, ow, out, (size_t)iB * 7);
    }
}

extern "C" void kernel_launch(void* const* d_in, const int* in_sizes, int n_in,
                              void* d_out, int out_size, void* d_ws, size_t ws_size,
                              hipStream_t stream) {
    const float* Twc   = (const float*)d_in[0];
    const float* Tp    = (const float*)d_in[1];
    const float* To    = (const float*)d_in[2];
    const float* pw    = (const float*)d_in[3];
    const float* ow    = (const float*)d_in[4];
    const int*   edges = (const int*)d_in[5];
    const float* Tlc   = (const float*)d_in[6];
    float* out = (float*)d_out;

    int n = in_sizes[1] / 8;   // N_FRAME - 1
    int half = (n + 1) / 2;
    const int block = 256;
    int grid = (half + block - 1) / block;
    pgo_kernel<<<grid, block, 0, stream>>>(Twc, Tp, To, pw, ow, edges, Tlc, out, n, half);
}

// Round 6
// 222.425 us; speedup vs baseline: 1.0028x; 1.0028x over previous
//
#include <hip/hip_runtime.h>
#include <math.h>

#define EPSF 1e-6f

typedef float  f32x4 __attribute__((ext_vector_type(4)));
typedef int    i32x2 __attribute__((ext_vector_type(2)));

struct F3   { float x, y, z; };
struct Quat { float x, y, z, w; };
struct Sim3 { F3 t; Quat q; float s; };

__device__ __forceinline__ float frcp(float x) { return __builtin_amdgcn_rcpf(x); }

__device__ __forceinline__ F3 cross3(F3 a, F3 b) {
    return { a.y*b.z - a.z*b.y, a.z*b.x - a.x*b.z, a.x*b.y - a.y*b.x };
}

__device__ __forceinline__ F3 quat_rotate(Quat q, F3 v) {
    F3 qv { q.x, q.y, q.z };
    F3 uv  = cross3(qv, v);
    F3 cuv = cross3(qv, uv);
    return { v.x + 2.0f*(q.w*uv.x + cuv.x),
             v.y + 2.0f*(q.w*uv.y + cuv.y),
             v.z + 2.0f*(q.w*uv.z + cuv.z) };
}

__device__ __forceinline__ Quat quat_mul(Quat a, Quat b) {
    return {
        a.w*b.x + a.x*b.w + a.y*b.z - a.z*b.y,
        a.w*b.y - a.x*b.z + a.y*b.w + a.z*b.x,
        a.w*b.z + a.x*b.y - a.y*b.x + a.z*b.w,
        a.w*b.w - a.x*b.x - a.y*b.y - a.z*b.z
    };
}

__device__ __forceinline__ Sim3 sim3_inv(Sim3 T) {
    Quat qi { -T.q.x, -T.q.y, -T.q.z, T.q.w };
    float si = frcp(T.s);
    F3 r = quat_rotate(qi, T.t);
    return { { -si*r.x, -si*r.y, -si*r.z }, qi, si };
}

__device__ __forceinline__ Sim3 sim3_mul(Sim3 A, Sim3 B) {
    F3 r = quat_rotate(A.q, B.t);
    return { { A.t.x + A.s*r.x, A.t.y + A.s*r.y, A.t.z + A.s*r.z },
             quat_mul(A.q, B.q), A.s * B.s };
}

__device__ __forceinline__ Sim3 load_sim3(const float* __restrict__ p) {
    f32x4 a = *reinterpret_cast<const f32x4*>(p);
    f32x4 b = *reinterpret_cast<const f32x4*>(p + 4);
    return { {a.x, a.y, a.z}, {a.w, b.x, b.y, b.z}, b.w };
}

// non-temporal (evict-first) loads for touch-once arrays
__device__ __forceinline__ Sim3 load_sim3_nt(const float* __restrict__ p) {
    f32x4 a = __builtin_nontemporal_load(reinterpret_cast<const f32x4*>(p));
    f32x4 b = __builtin_nontemporal_load(reinterpret_cast<const f32x4*>(p) + 1);
    return { {a.x, a.y, a.z}, {a.w, b.x, b.y, b.z}, b.w };
}

// atan2(y,x) for y >= 0, result in [0, pi]. Max abs err ~2e-7.
__device__ __forceinline__ float fast_atan2_pos(float y, float x) {
    float ax = fabsf(x);
    float mn = fminf(ax, y), mx = fmaxf(ax, y);
    float t  = mn * frcp(mx);
    float t2 = t * t;
    float p = fmaf(t2, -0.0117212f,  0.05265332f);
    p = fmaf(t2, p, -0.11643287f);
    p = fmaf(t2, p,  0.19354346f);
    p = fmaf(t2, p, -0.33262347f);
    p = fmaf(t2, p,  0.99997726f);
    float r = t * p;
    r = (y > ax)   ? 1.57079632679f - r : r;
    r = (x < 0.0f) ? 3.14159265359f - r : r;
    return r;
}

__device__ __forceinline__ void sim3_log(Sim3 T, float out[7]) {
    float qx = T.q.x, qy = T.q.y, qz = T.q.z, qw = T.q.w;
    float nv2 = fmaf(qx, qx, fmaf(qy, qy, qz*qz));
    float nv  = sqrtf(nv2);
    float theta_r = 2.0f * fast_atan2_pos(nv, qw);
    float fac = (nv < EPSF) ? 2.0f : theta_r * frcp(nv);
    float px = fac*qx, py = fac*qy, pz = fac*qz;
    float sigma = __logf(T.s);
    float theta = sqrtf(fmaf(px, px, fmaf(py, py, pz*pz)));

    bool sig_small = fabsf(sigma) < EPSF;
    bool th_small  = theta < EPSF;
    float sg = sig_small ? 1.0f : sigma;
    float th = th_small  ? 1.0f : theta;
    float scale = __expf(sigma);
    float th2 = th*th, sg2 = sg*sg;
    float rsg  = frcp(sg);
    float rth2 = frcp(th2);
    float C = sig_small ? 1.0f : (scale - 1.0f) * rsg;

    // sin(theta), cos(theta) via quaternion half-angle identity
    float inv_q = frcp(nv2 + qw*qw);
    float sth = 2.0f * qw * nv * inv_q;
    float cth = (qw*qw - nv2) * inv_q;

    float A_ss = th_small ? 0.5f        : (1.0f - cth) * rth2;
    float B_ss = th_small ? (1.0f/6.0f) : (th - sth) * frcp(th2 * th);
    float a = scale * sth;
    float b = scale * cth;
    float c = th2 + sg2;
    float rc = frcp(c);
    float A_g = fmaf(a, sg, (1.0f - b)*th) * frcp(th * c);
    float B_g = (C - fmaf(b - 1.0f, sg, a*th) * rc) * rth2;
    float rsg2 = rsg * rsg;
    float A_ts = fmaf(sg - 1.0f, scale, 1.0f) * rsg2;
    float B_ts = fmaf(scale, fmaf(sg, sg - 2.0f, 2.0f), -2.0f) * (0.5f * rsg2 * rsg);
    float A = sig_small ? A_ss : (th_small ? A_ts : A_g);
    float B = sig_small ? B_ss : (th_small ? B_ts : B_g);

    float P01 = -pz, P02 =  py;
    float P10 =  pz, P12 = -px;
    float P20 = -py, P21 =  px;
    float Q00 = P01*P10 + P02*P20;
    float Q01 = P02*P21;
    float Q02 = P01*P12;
    float Q10 = P12*P20;
    float Q11 = P10*P01 + P12*P21;
    float Q12 = P10*P02;
    float Q20 = P21*P10;
    float Q21 = P20*P01;
    float Q22 = P20*P02 + P21*P12;

    float W00 = fmaf(B, Q00, C);
    float W01 = fmaf(A, P01, B*Q01);
    float W02 = fmaf(A, P02, B*Q02);
    float W10 = fmaf(A, P10, B*Q10);
    float W11 = fmaf(B, Q11, C);
    float W12 = fmaf(A, P12, B*Q12);
    float W20 = fmaf(A, P20, B*Q20);
    float W21 = fmaf(A, P21, B*Q21);
    float W22 = fmaf(B, Q22, C);

    float c00 = fmaf(W11, W22, -W12*W21);
    float c01 = fmaf(W12, W20, -W10*W22);
    float c02 = fmaf(W10, W21, -W11*W20);
    float det = fmaf(W00, c00, fmaf(W01, c01, W02*c02));
    float idet = frcp(det);
    float m01 = fmaf(W02, W21, -W01*W22);
    float m02 = fmaf(W01, W12, -W02*W11);
    float m11 = fmaf(W00, W22, -W02*W20);
    float m12 = fmaf(W02, W10, -W00*W12);
    float m21 = fmaf(W01, W20, -W00*W21);
    float m22 = fmaf(W00, W11, -W01*W10);
    float tx = T.t.x, ty = T.t.y, tz = T.t.z;
    out[0] = fmaf(c00, tx, fmaf(m01, ty, m02*tz)) * idet;
    out[1] = fmaf(c01, tx, fmaf(m11, ty, m12*tz)) * idet;
    out[2] = fmaf(c02, tx, fmaf(m21, ty, m22*tz)) * idet;
    out[3] = px; out[4] = py; out[5] = pz; out[6] = sigma;
}

#define R 4

// 4 rows per thread, software-pipelined one row ahead. sched_barrier(0)
// fences pin the prefetch groups so the compiler cannot sink loads to their
// uses (R5's VGPR=52 showed it collapses the pipeline otherwise).
__global__ void __launch_bounds__(256) pgo_kernel(
        const float* __restrict__ Twc,
        const float* __restrict__ Tp_inv,
        const float* __restrict__ To_inv,
        const float* __restrict__ pw,
        const float* __restrict__ ow,
        const int*   __restrict__ edges,
        const float* __restrict__ T_lc,
        float*       __restrict__ out,
        int n, int q) {
    int t = blockIdx.x * blockDim.x + threadIdx.x;
    if (t >= q) return;

    int   ic[R];
    bool  val[R];
    #pragma unroll
    for (int k = 0; k < R; ++k) {
        int idx = t + k * q;
        val[k] = (idx < n);
        ic[k]  = val[k] ? idx : 0;
    }

    // All edge indices up front (cheap, streamed).
    i32x2 e[R];
    #pragma unroll
    for (int k = 0; k < R; ++k)
        e[k] = *(reinterpret_cast<const i32x2*>(edges) + ic[k]);

    // Double-buffered register slots for the in-flight row.
    Sim3 Ta[2], Tb[2], Ti[2], Tj[2], Tp[2], To[2], Tl[2];

    // Prologue: prefetch row 0 into slot 0.
    {
        size_t r8 = (size_t)ic[0] * 8;
        Ta[0] = load_sim3(Twc + (size_t)e[0].x * 8);
        Tb[0] = load_sim3(Twc + (size_t)e[0].y * 8);
        Ti[0] = load_sim3(Twc + r8);
        Tj[0] = load_sim3(Twc + r8 + 8);
        Tp[0] = load_sim3_nt(Tp_inv + r8);
        To[0] = load_sim3_nt(To_inv + r8);
        Tl[0] = load_sim3_nt(T_lc + r8);
    }

    #pragma unroll
    for (int k = 0; k < R; ++k) {
        const int cur = k & 1, nxt = cur ^ 1;

        // Prefetch row k+1 while computing row k.
        if (k + 1 < R) {
            size_t r8 = (size_t)ic[k+1] * 8;
            Ta[nxt] = load_sim3(Twc + (size_t)e[k+1].x * 8);
            Tb[nxt] = load_sim3(Twc + (size_t)e[k+1].y * 8);
            Ti[nxt] = load_sim3(Twc + r8);
            Tj[nxt] = load_sim3(Twc + r8 + 8);
            Tp[nxt] = load_sim3_nt(Tp_inv + r8);
            To[nxt] = load_sim3_nt(To_inv + r8);
            Tl[nxt] = load_sim3_nt(T_lc + r8);
        }
        __builtin_amdgcn_sched_barrier(0);   // pin prefetch above compute

        Sim3 delta = sim3_mul(sim3_inv(Ti[cur]), Tj[cur]);
        float rp[7], ro[7], rl[7];
        sim3_log(sim3_mul(delta, Tp[cur]), rp);
        sim3_log(sim3_mul(delta, To[cur]), ro);
        sim3_log(sim3_mul(sim3_mul(sim3_inv(Ta[cur]), Tb[cur]), Tl[cur]), rl);

        if (val[k]) {
            size_t i7 = (size_t)ic[k] * 7;
            #pragma unroll
            for (int j = 0; j < 7; ++j) {
                float w1 = __builtin_nontemporal_load(pw + i7 + j);
                float w2 = __builtin_nontemporal_load(ow + i7 + j);
                out[i7 + j] = fmaf(rp[j], w1, fmaf(ro[j], w2, rl[j]));
            }
        }
        __builtin_amdgcn_sched_barrier(0);   // keep stages separated
    }
}

extern "C" void kernel_launch(void* const* d_in, const int* in_sizes, int n_in,
                              void* d_out, int out_size, void* d_ws, size_t ws_size,
                              hipStream_t stream) {
    const float* Twc   = (const float*)d_in[0];
    const float* Tp    = (const float*)d_in[1];
    const float* To    = (const float*)d_in[2];
    const float* pw    = (const float*)d_in[3];
    const float* ow    = (const float*)d_in[4];
    const int*   edges = (const int*)d_in[5];
    const float* Tlc   = (const float*)d_in[6];
    float* out = (float*)d_out;

    int n = in_sizes[1] / 8;   // N_FRAME - 1
    int q = (n + R - 1) / R;
    const int block = 256;
    int grid = (q + block - 1) / block;
    pgo_kernel<<<grid, block, 0, stream>>>(Twc, Tp, To, pw, ow, edges, Tlc, out, n, q);
}